// Round 7
// baseline (52.794 us; speedup 1.0000x reference)
//
#include <hip/hip_runtime.h>
#include <stdint.h>

// BaseRenderer: NeRF-style compositing with per-ray depth sort.
// v7: 2 rays per wave, FULLY INTERLEAVED (ILP-2 across rays, ILP-4 in sort).
// rgb/inst staged to LDS via global_load_lds, consumed by gather at sorted
// indices (no w inverse-perm round trip). Zero barriers, single vmcnt(0)
// drain, block=128 -> 12.3KB LDS/block -> 13 blocks/CU.

typedef unsigned long long u64;

// ---------------- DPP helpers ----------------
template<int CTRL, int RM>
__device__ __forceinline__ float updpp_f(float oldv, float src) {
    return __uint_as_float((uint32_t)__builtin_amdgcn_update_dpp(
        (int)__float_as_uint(oldv), (int)__float_as_uint(src), CTRL, RM, 0xF, false));
}

template<int CTRL>
__device__ __forceinline__ uint32_t dppmov_u(uint32_t v) {
    return (uint32_t)__builtin_amdgcn_mov_dpp((int)v, CTRL, 0xF, 0xF, true);
}

// 6-op DPP reduction; full-wave total lands in lane 63.
__device__ __forceinline__ float red6(float x) {
    x += updpp_f<0x111, 0xF>(0.0f, x);   // row_shr:1
    x += updpp_f<0x112, 0xF>(0.0f, x);   // row_shr:2
    x += updpp_f<0x114, 0xF>(0.0f, x);   // row_shr:4
    x += updpp_f<0x118, 0xF>(0.0f, x);   // row_shr:8
    x += updpp_f<0x142, 0xA>(0.0f, x);   // row_bcast:15 -> rows 1,3
    x += updpp_f<0x143, 0xC>(0.0f, x);   // row_bcast:31 -> rows 2,3
    return x;
}

// ---------------- 32-bit bitonic sort (fast path) ----------------
template<int LJ>
__device__ __forceinline__ uint32_t xp(uint32_t k) {
    if constexpr (LJ == 1)      return dppmov_u<0xB1>(k);    // quad_perm xor1
    else if constexpr (LJ == 2) return dppmov_u<0x4E>(k);    // quad_perm xor2
    else if constexpr (LJ == 8) return dppmov_u<0x128>(k);   // row_ror:8 == xor8
    else return (uint32_t)__shfl_xor((int)k, LJ, 64);        // xor4/16/32 via DS
}

template<int LJ>
__device__ __forceinline__ void crossce(uint32_t& a, uint32_t& b, bool dirbit, int lane) {
    uint32_t pa = xp<LJ>(a);
    uint32_t pb = xp<LJ>(b);
    const bool keepmin = (((lane & LJ) == 0) == dirbit);
    a = ((pa < a) == keepmin) ? pa : a;    // keys unique -> no ties
    b = ((pb < b) == keepmin) ? pb : b;
    if constexpr (LJ > 1) crossce<LJ / 2>(a, b, dirbit, lane);
}

template<int K>
__device__ __forceinline__ void phase32(uint32_t& a, uint32_t& b, int lane) {
    const bool dirbit = ((lane & (K >> 1)) == 0);
    if constexpr (K >= 4) crossce<K / 4>(a, b, dirbit, lane);
    const bool sw = ((b < a) == dirbit);   // intra-lane step
    uint32_t t = a;
    a = sw ? b : a;
    b = sw ? t : b;
}

__device__ __forceinline__ void sort128(uint32_t& a, uint32_t& b, int lane) {
    phase32<2>(a, b, lane);
    phase32<4>(a, b, lane);
    phase32<8>(a, b, lane);
    phase32<16>(a, b, lane);
    phase32<32>(a, b, lane);
    phase32<64>(a, b, lane);
    phase32<128>(a, b, lane);
}

// ---------------- 64-bit fallback sort ----------------
__device__ __forceinline__ u64 shfl_xor_u64(u64 v, int mask) {
    int lo = __shfl_xor((int)(uint32_t)v, mask, 64);
    int hi = __shfl_xor((int)(uint32_t)(v >> 32), mask, 64);
    return ((u64)(uint32_t)hi << 32) | (uint32_t)lo;
}

__device__ __forceinline__ void sort128_u64(float2 zv, int lane,
                                            uint32_t& i0, uint32_t& i1,
                                            float& zs0, float& zs1) {
    u64 a = ((u64)__float_as_uint(zv.x) << 7) | (u64)(2 * lane);
    u64 b = ((u64)__float_as_uint(zv.y) << 7) | (u64)(2 * lane + 1);
    #pragma unroll
    for (int k = 2; k <= 128; k <<= 1) {
        #pragma unroll
        for (int j = k >> 1; j >= 2; j >>= 1) {
            const int lj = j >> 1;
            u64 pa = shfl_xor_u64(a, lj);
            u64 pb = shfl_xor_u64(b, lj);
            const bool keepmin = (((lane & lj) == 0) == ((lane & (k >> 1)) == 0));
            a = ((pa < a) == keepmin) ? pa : a;
            b = ((pb < b) == keepmin) ? pb : b;
        }
        const bool asc = ((lane & (k >> 1)) == 0);
        const bool sw = ((b < a) == asc);
        u64 t = a;
        a = sw ? b : a;
        b = sw ? t : b;
    }
    i0 = (uint32_t)(a & 127u);
    i1 = (uint32_t)(b & 127u);
    zs0 = __uint_as_float((uint32_t)(a >> 7));
    zs1 = __uint_as_float((uint32_t)(b >> 7));
}

#define GLL16(gsrc, ldst) __builtin_amdgcn_global_load_lds(                    \
    (const __attribute__((address_space(1))) void*)(gsrc),                     \
    (__attribute__((address_space(3))) void*)(ldst), 16, 0, 0)

// Per-ray epilogue. slab: [rgb 0..383 | inst 384..767] in original order.
__device__ __forceinline__ void finish(uint32_t i0, uint32_t i1,
                                       float zs0, float zs1, float2 sv,
                                       int ray, int lane,
                                       const float* __restrict__ slab,
                                       float bg0, float bg1, float bg2,
                                       float* __restrict__ out, int N)
{
    constexpr float INF_DIST = 1e10f;
    constexpr float EPS = 1e-10f;

    // ---- gather sigma by original index (bpermute) ----
    float s0a = __shfl(sv.x, (int)(i0 >> 1), 64);
    float s0b = __shfl(sv.y, (int)(i0 >> 1), 64);
    float s1a = __shfl(sv.x, (int)(i1 >> 1), 64);
    float s1b = __shfl(sv.y, (int)(i1 >> 1), 64);
    float sg0 = (i0 & 1) ? s0b : s0a;
    float sg1 = (i1 & 1) ? s1b : s1a;

    // ---- rgb/inst gathers at sorted indices (issue early; overlap scan) ----
    const float* pA = slab + i0 * 3;
    const float* pB = slab + i1 * 3;
    float rA0 = pA[0],   rA1 = pA[1],   rA2 = pA[2];
    float qA0 = pA[384], qA1 = pA[385], qA2 = pA[386];
    float rB0 = pB[0],   rB1 = pB[1],   rB2 = pB[2];
    float qB0 = pB[384], qB1 = pB[385], qB2 = pB[386];

    // ---- dists; lane63 boundary via DPP old=INF ----
    float znx = updpp_f<0x130, 0xF>(INF_DIST, zs0);   // wave_shl:1
    float d0 = zs1 - zs0;
    float d1 = znx - zs1;

    // ---- alpha / transmittance factors ----
    float e0 = __expf(-fmaxf(sg0, 0.0f) * d0);
    float e1 = __expf(-fmaxf(sg1, 0.0f) * d1);
    float a0 = 1.0f - e0;
    float a1 = 1.0f - e1;
    float m0 = 1.0f - a0 + EPS;
    float m1 = 1.0f - a1 + EPS;

    // ---- DPP multiply-scan (inclusive), identity 1.0 ----
    float s = m0 * m1;
    s *= updpp_f<0x111, 0xF>(1.0f, s);
    s *= updpp_f<0x112, 0xF>(1.0f, s);
    s *= updpp_f<0x114, 0xF>(1.0f, s);
    s *= updpp_f<0x118, 0xF>(1.0f, s);
    s *= updpp_f<0x142, 0xA>(1.0f, s);
    s *= updpp_f<0x143, 0xC>(1.0f, s);

    float excl = updpp_f<0x138, 0xF>(1.0f, s);        // wave_shr:1, lane0 -> 1.0

    float w0 = a0 * excl;
    float w1 = a1 * (excl * m0);

    // ---- weighted partials (sorted domain; same sums as reference) ----
    float dep = w0 * zs0 + w1 * zs1;
    float cr = w0 * rA0 + w1 * rB0;
    float cg = w0 * rA1 + w1 * rB1;
    float cb = w0 * rA2 + w1 * rB2;
    float k0 = w0 * qA0 + w1 * qB0;
    float k1 = w0 * qA1 + w1 * qB1;
    float k2 = w0 * qA2 + w1 * qB2;

    // ---- DPP reductions; totals land in lane 63 ----
    dep = red6(dep);
    cr  = red6(cr);
    cg  = red6(cg);
    cb  = red6(cb);
    k0  = red6(k0);
    k1  = red6(k1);
    k2  = red6(k2);

    // ---- stores last (never waited on) ----
    {
        u64 wbits = ((u64)__float_as_uint(w1) << 32) | (u64)__float_as_uint(w0);
        __builtin_nontemporal_store(wbits,
            (u64*)(out + (size_t)7 * N + (size_t)ray * 128) + lane);
    }
    if (lane == 63) {
        float no_hit = s;
        out[(size_t)ray * 3 + 0] = cr + no_hit * bg0;
        out[(size_t)ray * 3 + 1] = cg + no_hit * bg1;
        out[(size_t)ray * 3 + 2] = cb + no_hit * bg2;
        out[(size_t)3 * N + ray] = dep;
        out[(size_t)4 * N + (size_t)ray * 3 + 0] = k0;
        out[(size_t)4 * N + (size_t)ray * 3 + 1] = k1;
        out[(size_t)4 * N + (size_t)ray * 3 + 2] = k2;
    }
}

__global__ __launch_bounds__(128) void render_kernel(
    const float* __restrict__ z_vals,
    const float* __restrict__ sigma_vals,
    const float* __restrict__ rgb_vals,
    const float* __restrict__ inst_vals,
    const float* __restrict__ bg_color,
    float* __restrict__ out,
    int N)
{
    const int lane = threadIdx.x & 63;
    const int wib  = threadIdx.x >> 6;            // 0..1 (2 waves/block)
    const int wid  = blockIdx.x * 2 + wib;

    // [wave][ray][ rgb 384 | inst 384 ]  -> 12,288 B/block
    __shared__ float lds[2][2][768];

    int ray0 = 2 * wid;
    int ray1 = 2 * wid + 1;
    if (ray0 >= N) return;
    if (ray1 >= N) ray1 = ray0;                   // duplicate-safe clamp

    const size_t rb0 = (size_t)ray0 * 128;
    const size_t rb1 = (size_t)ray1 * 128;

    // ---- issue ALL VMEM up front ----
    float2 zv0 = ((const float2*)(z_vals     + rb0))[lane];
    float2 sv0 = ((const float2*)(sigma_vals + rb0))[lane];
    float2 zv1 = ((const float2*)(z_vals     + rb1))[lane];
    float2 sv1 = ((const float2*)(sigma_vals + rb1))[lane];

    float* s0 = &lds[wib][0][0];
    float* s1 = &lds[wib][1][0];
    {
        const char* r0p = (const char*)(rgb_vals  + rb0 * 3);
        const char* i0p = (const char*)(inst_vals + rb0 * 3);
        const char* r1p = (const char*)(rgb_vals  + rb1 * 3);
        const char* i1p = (const char*)(inst_vals + rb1 * 3);
        char* rd0 = (char*)s0;
        char* id0 = (char*)(s0 + 384);
        char* rd1 = (char*)s1;
        char* id1 = (char*)(s1 + 384);
        GLL16(r0p + (size_t)lane * 16, rd0);
        GLL16(i0p + (size_t)lane * 16, id0);
        GLL16(r1p + (size_t)lane * 16, rd1);
        GLL16(i1p + (size_t)lane * 16, id1);
        if (lane < 32) {
            GLL16(r0p + 1024 + (size_t)lane * 16, rd0 + 1024);
            GLL16(i0p + 1024 + (size_t)lane * 16, id0 + 1024);
            GLL16(r1p + 1024 + (size_t)lane * 16, rd1 + 1024);
            GLL16(i1p + 1024 + (size_t)lane * 16, id1 + 1024);
        }
    }
    __builtin_amdgcn_sched_barrier(0);            // pin all issues above compute

    // ---- bg: wave-uniform scalar loads ----
    float bg00 = bg_color[(size_t)ray0 * 3 + 0];
    float bg01 = bg_color[(size_t)ray0 * 3 + 1];
    float bg02 = bg_color[(size_t)ray0 * 3 + 2];
    float bg10 = bg_color[(size_t)ray1 * 3 + 0];
    float bg11 = bg_color[(size_t)ray1 * 3 + 1];
    float bg12 = bg_color[(size_t)ray1 * 3 + 2];

    // ---- dyadic check for all 4 z pairs (exact for JAX uniform*4) ----
    float f00 = zv0.x * 2097152.0f, f01 = zv0.y * 2097152.0f;
    float f10 = zv1.x * 2097152.0f, f11 = zv1.y * 2097152.0f;
    uint32_t m00 = (uint32_t)f00, m01 = (uint32_t)f01;
    uint32_t m10 = (uint32_t)f10, m11 = (uint32_t)f11;
    bool exact = (f00 == (float)m00) && (f01 == (float)m01) &&
                 (f10 == (float)m10) && (f11 == (float)m11) &&
                 (m00 < (1u << 23)) && (m01 < (1u << 23)) &&
                 (m10 < (1u << 23)) && (m11 < (1u << 23));

    uint32_t i00, i01, i10, i11;
    float zs00, zs01, zs10, zs11;

    if (__ballot(exact) == ~0ull) {
        // ---- fast: 32-bit keys, both rays interleaved (ILP-4 chains) ----
        uint32_t a0 = (m00 << 7) | (uint32_t)(2 * lane);
        uint32_t b0 = (m01 << 7) | (uint32_t)(2 * lane + 1);
        uint32_t a1 = (m10 << 7) | (uint32_t)(2 * lane);
        uint32_t b1 = (m11 << 7) | (uint32_t)(2 * lane + 1);
        sort128(a0, b0, lane);
        sort128(a1, b1, lane);
        i00 = a0 & 127u; i01 = b0 & 127u;
        i10 = a1 & 127u; i11 = b1 & 127u;
        zs00 = (float)(a0 >> 7) * 0x1p-21f;      // bit-exact z recovery
        zs01 = (float)(b0 >> 7) * 0x1p-21f;
        zs10 = (float)(a1 >> 7) * 0x1p-21f;
        zs11 = (float)(b1 >> 7) * 0x1p-21f;
    } else {
        sort128_u64(zv0, lane, i00, i01, zs00, zs01);
        sort128_u64(zv1, lane, i10, i11, zs10, zs11);
    }

    // ---- single drain: gll slabs now resident (issued ~sort-duration ago) ----
    asm volatile("s_waitcnt vmcnt(0)" ::: "memory");
    __builtin_amdgcn_sched_barrier(0);

    // ---- epilogues, interleaved by the scheduler ----
    finish(i00, i01, zs00, zs01, sv0, ray0, lane, s0, bg00, bg01, bg02, out, N);
    finish(i10, i11, zs10, zs11, sv1, ray1, lane, s1, bg10, bg11, bg12, out, N);
}

extern "C" void kernel_launch(void* const* d_in, const int* in_sizes, int n_in,
                              void* d_out, int out_size, void* d_ws, size_t ws_size,
                              hipStream_t stream)
{
    const float* z    = (const float*)d_in[0];
    const float* sg   = (const float*)d_in[1];
    const float* rgb  = (const float*)d_in[2];
    const float* inst = (const float*)d_in[3];
    const float* bg   = (const float*)d_in[4];
    float* out = (float*)d_out;

    const int S = 128;
    int N = in_sizes[0] / S;                  // 65536
    int waves = (N + 1) / 2;                  // 2 rays per wave
    int blocks = (waves + 1) / 2;             // 2 waves per 128-thread block
    render_kernel<<<blocks, 128, 0, stream>>>(z, sg, rgb, inst, bg, out, N);
}

// Round 8
// 48.804 us; speedup vs baseline: 1.0818x; 1.0818x over previous
//
#include <hip/hip_runtime.h>
#include <stdint.h>

// BaseRenderer: NeRF-style compositing with per-ray depth sort.
// v8: 1 ray/wave (max TLP: 32 waves/CU), barrier-free, gll slab staging,
// sort chain de-DS'd: xor16/xor32 via gfx950 permlane{16,32}_swap (VALU),
// only xor4 remains on the DS pipe. Gather epilogue at sorted indices.

typedef unsigned long long u64;
typedef int v2i __attribute__((ext_vector_type(2)));

// ---------------- DPP helpers ----------------
template<int CTRL, int RM>
__device__ __forceinline__ float updpp_f(float oldv, float src) {
    return __uint_as_float((uint32_t)__builtin_amdgcn_update_dpp(
        (int)__float_as_uint(oldv), (int)__float_as_uint(src), CTRL, RM, 0xF, false));
}

template<int CTRL>
__device__ __forceinline__ uint32_t dppmov_u(uint32_t v) {
    return (uint32_t)__builtin_amdgcn_mov_dpp((int)v, CTRL, 0xF, 0xF, true);
}

// 6-op DPP reduction; full-wave total lands in lane 63.
__device__ __forceinline__ float red6(float x) {
    x += updpp_f<0x111, 0xF>(0.0f, x);   // row_shr:1
    x += updpp_f<0x112, 0xF>(0.0f, x);   // row_shr:2
    x += updpp_f<0x114, 0xF>(0.0f, x);   // row_shr:4
    x += updpp_f<0x118, 0xF>(0.0f, x);   // row_shr:8
    x += updpp_f<0x142, 0xA>(0.0f, x);   // row_bcast:15 -> rows 1,3
    x += updpp_f<0x143, 0xC>(0.0f, x);   // row_bcast:31 -> rows 2,3
    return x;
}

// ---------------- cross-lane partner fetch, lane^LJ ----------------
// xor1/2: quad_perm DPP. xor8: row_ror:8. xor16/32: permlane swap (VALU) with
// the direction-independent identity: {r.x,r.y}={x[l],x[l^d]} per lane, so
// partner = r.x ^ r.y ^ x. Only xor4 remains on the DS pipe.
template<int LJ>
__device__ __forceinline__ uint32_t xp(uint32_t k) {
    if constexpr (LJ == 1)       return dppmov_u<0xB1>(k);    // quad_perm [1,0,3,2]
    else if constexpr (LJ == 2)  return dppmov_u<0x4E>(k);    // quad_perm [2,3,0,1]
    else if constexpr (LJ == 4)  return (uint32_t)__builtin_amdgcn_ds_swizzle((int)k, 0x101F);
    else if constexpr (LJ == 8)  return dppmov_u<0x128>(k);   // row_ror:8 == xor8
    else if constexpr (LJ == 16) {
        v2i r = __builtin_amdgcn_permlane16_swap((int)k, (int)k, false, false);
        return ((uint32_t)r.x ^ (uint32_t)r.y) ^ k;
    } else {
        v2i r = __builtin_amdgcn_permlane32_swap((int)k, (int)k, false, false);
        return ((uint32_t)r.x ^ (uint32_t)r.y) ^ k;
    }
}

template<int LJ>
__device__ __forceinline__ void crossce(uint32_t& a, uint32_t& b, bool dirbit, int lane) {
    uint32_t pa = xp<LJ>(a);
    uint32_t pb = xp<LJ>(b);
    const bool keepmin = (((lane & LJ) == 0) == dirbit);
    a = ((pa < a) == keepmin) ? pa : a;    // keys unique -> no ties
    b = ((pb < b) == keepmin) ? pb : b;
    if constexpr (LJ > 1) crossce<LJ / 2>(a, b, dirbit, lane);
}

template<int K>
__device__ __forceinline__ void phase32(uint32_t& a, uint32_t& b, int lane) {
    const bool dirbit = ((lane & (K >> 1)) == 0);
    if constexpr (K >= 4) crossce<K / 4>(a, b, dirbit, lane);
    const bool sw = ((b < a) == dirbit);   // intra-lane step
    uint32_t t = a;
    a = sw ? b : a;
    b = sw ? t : b;
}

__device__ __forceinline__ void sort128(uint32_t& a, uint32_t& b, int lane) {
    phase32<2>(a, b, lane);
    phase32<4>(a, b, lane);
    phase32<8>(a, b, lane);
    phase32<16>(a, b, lane);
    phase32<32>(a, b, lane);
    phase32<64>(a, b, lane);
    phase32<128>(a, b, lane);
}

// ---------------- 64-bit fallback sort ----------------
__device__ __forceinline__ u64 shfl_xor_u64(u64 v, int mask) {
    int lo = __shfl_xor((int)(uint32_t)v, mask, 64);
    int hi = __shfl_xor((int)(uint32_t)(v >> 32), mask, 64);
    return ((u64)(uint32_t)hi << 32) | (uint32_t)lo;
}

__device__ __forceinline__ void sort128_u64(float2 zv, int lane,
                                            uint32_t& i0, uint32_t& i1,
                                            float& zs0, float& zs1) {
    u64 a = ((u64)__float_as_uint(zv.x) << 7) | (u64)(2 * lane);
    u64 b = ((u64)__float_as_uint(zv.y) << 7) | (u64)(2 * lane + 1);
    #pragma unroll
    for (int k = 2; k <= 128; k <<= 1) {
        #pragma unroll
        for (int j = k >> 1; j >= 2; j >>= 1) {
            const int lj = j >> 1;
            u64 pa = shfl_xor_u64(a, lj);
            u64 pb = shfl_xor_u64(b, lj);
            const bool keepmin = (((lane & lj) == 0) == ((lane & (k >> 1)) == 0));
            a = ((pa < a) == keepmin) ? pa : a;
            b = ((pb < b) == keepmin) ? pb : b;
        }
        const bool asc = ((lane & (k >> 1)) == 0);
        const bool sw = ((b < a) == asc);
        u64 t = a;
        a = sw ? b : a;
        b = sw ? t : b;
    }
    i0 = (uint32_t)(a & 127u);
    i1 = (uint32_t)(b & 127u);
    zs0 = __uint_as_float((uint32_t)(a >> 7));
    zs1 = __uint_as_float((uint32_t)(b >> 7));
}

#define GLL16(gsrc, ldst) __builtin_amdgcn_global_load_lds(                    \
    (const __attribute__((address_space(1))) void*)(gsrc),                     \
    (__attribute__((address_space(3))) void*)(ldst), 16, 0, 0)

__global__ __launch_bounds__(256) void render_kernel(
    const float* __restrict__ z_vals,
    const float* __restrict__ sigma_vals,
    const float* __restrict__ rgb_vals,
    const float* __restrict__ inst_vals,
    const float* __restrict__ bg_color,
    float* __restrict__ out,
    int N)
{
    constexpr float INF_DIST = 1e10f;
    constexpr float EPS = 1e-10f;

    const int lane = threadIdx.x & 63;
    const int wib  = threadIdx.x >> 6;            // 0..3 (4 waves/block)
    int ray = blockIdx.x * 4 + wib;
    if (ray >= N) ray = N - 1;                    // clamp (barrier-free, safe dup)

    // per-wave slab: [ rgb 0..383 | inst 384..767 ]  -> 12,288 B/block
    __shared__ float lds[4][768];
    float* slab = &lds[wib][0];

    const size_t rbase = (size_t)ray * 128;

    // ---- issue ALL VMEM up front ----
    float2 zv = ((const float2*)(z_vals     + rbase))[lane];
    float2 sv = ((const float2*)(sigma_vals + rbase))[lane];
    {
        const char* rp = (const char*)(rgb_vals  + rbase * 3);
        const char* ip = (const char*)(inst_vals + rbase * 3);
        char* rd = (char*)slab;
        char* id = (char*)(slab + 384);
        GLL16(rp + (size_t)lane * 16, rd);                  // rgb  [0,1024)
        GLL16(ip + (size_t)lane * 16, id);                  // inst [0,1024)
        if (lane < 32) {
            GLL16(rp + 1024 + (size_t)lane * 16, rd + 1024);
            GLL16(ip + 1024 + (size_t)lane * 16, id + 1024);
        }
    }
    __builtin_amdgcn_sched_barrier(0);            // pin issues above compute

    // ---- bg: wave-uniform scalar loads (SMEM pipe) ----
    float bg0 = bg_color[(size_t)ray * 3 + 0];
    float bg1 = bg_color[(size_t)ray * 3 + 1];
    float bg2 = bg_color[(size_t)ray * 3 + 2];

    // ---- dyadic check: z == m / 2^21, m < 2^23 (exact for JAX uniform*4) ----
    float k0f = zv.x * 2097152.0f;
    float k1f = zv.y * 2097152.0f;
    uint32_t m0i = (uint32_t)k0f;
    uint32_t m1i = (uint32_t)k1f;
    bool exact = (k0f == (float)m0i) && (k1f == (float)m1i) &&
                 (m0i < (1u << 23)) && (m1i < (1u << 23));

    uint32_t i0, i1;
    float zs0, zs1;

    if (__ballot(exact) == ~0ull) {
        uint32_t a = (m0i << 7) | (uint32_t)(2 * lane);
        uint32_t b = (m1i << 7) | (uint32_t)(2 * lane + 1);
        sort128(a, b, lane);
        i0 = a & 127u;
        i1 = b & 127u;
        zs0 = (float)(a >> 7) * 0x1p-21f;         // bit-exact z recovery
        zs1 = (float)(b >> 7) * 0x1p-21f;
    } else {
        sort128_u64(zv, lane, i0, i1, zs0, zs1);
    }

    // ---- gather sigma by original index (bpermute; issue asap) ----
    float s0a = __shfl(sv.x, (int)(i0 >> 1), 64);
    float s0b = __shfl(sv.y, (int)(i0 >> 1), 64);
    float s1a = __shfl(sv.x, (int)(i1 >> 1), 64);
    float s1b = __shfl(sv.y, (int)(i1 >> 1), 64);
    float sg0 = (i0 & 1) ? s0b : s0a;
    float sg1 = (i1 & 1) ? s1b : s1a;

    // ---- drain: gll slab now resident (issued ~sort ago; per-wave, no barrier) ----
    asm volatile("s_waitcnt vmcnt(0)" ::: "memory");
    __builtin_amdgcn_sched_barrier(0);

    // ---- rgb/inst gathers at sorted indices (DS; overlap the scan below) ----
    const float* pA = slab + i0 * 3;
    const float* pB = slab + i1 * 3;
    float rA0 = pA[0],   rA1 = pA[1],   rA2 = pA[2];
    float qA0 = pA[384], qA1 = pA[385], qA2 = pA[386];
    float rB0 = pB[0],   rB1 = pB[1],   rB2 = pB[2];
    float qB0 = pB[384], qB1 = pB[385], qB2 = pB[386];

    // ---- dists; lane63 boundary via DPP old=INF ----
    float znx = updpp_f<0x130, 0xF>(INF_DIST, zs0);   // wave_shl:1
    float d0 = zs1 - zs0;
    float d1 = znx - zs1;

    // ---- alpha / transmittance factors ----
    float e0 = __expf(-fmaxf(sg0, 0.0f) * d0);
    float e1 = __expf(-fmaxf(sg1, 0.0f) * d1);
    float a0 = 1.0f - e0;
    float a1 = 1.0f - e1;
    float m0 = 1.0f - a0 + EPS;
    float m1 = 1.0f - a1 + EPS;

    // ---- DPP multiply-scan (inclusive), identity 1.0 ----
    float s = m0 * m1;
    s *= updpp_f<0x111, 0xF>(1.0f, s);
    s *= updpp_f<0x112, 0xF>(1.0f, s);
    s *= updpp_f<0x114, 0xF>(1.0f, s);
    s *= updpp_f<0x118, 0xF>(1.0f, s);
    s *= updpp_f<0x142, 0xA>(1.0f, s);
    s *= updpp_f<0x143, 0xC>(1.0f, s);

    float excl = updpp_f<0x138, 0xF>(1.0f, s);        // wave_shr:1, lane0 -> 1.0

    float w0 = a0 * excl;
    float w1 = a1 * (excl * m0);

    // ---- w output (sorted order), nontemporal, issued early ----
    {
        u64 wbits = ((u64)__float_as_uint(w1) << 32) | (u64)__float_as_uint(w0);
        __builtin_nontemporal_store(wbits, (u64*)(out + (size_t)7 * N + rbase) + lane);
    }

    // ---- weighted partials (sorted domain; same sums as reference) ----
    float dep = w0 * zs0 + w1 * zs1;
    float cr = w0 * rA0 + w1 * rB0;
    float cg = w0 * rA1 + w1 * rB1;
    float cb = w0 * rA2 + w1 * rB2;
    float k0 = w0 * qA0 + w1 * qB0;
    float k1 = w0 * qA1 + w1 * qB1;
    float k2 = w0 * qA2 + w1 * qB2;

    // ---- DPP reductions; totals land in lane 63 ----
    dep = red6(dep);
    cr  = red6(cr);
    cg  = red6(cg);
    cb  = red6(cb);
    k0  = red6(k0);
    k1  = red6(k1);
    k2  = red6(k2);

    if (lane == 63) {
        float no_hit = s;
        out[(size_t)ray * 3 + 0] = cr + no_hit * bg0;
        out[(size_t)ray * 3 + 1] = cg + no_hit * bg1;
        out[(size_t)ray * 3 + 2] = cb + no_hit * bg2;
        out[(size_t)3 * N + ray] = dep;
        out[(size_t)4 * N + (size_t)ray * 3 + 0] = k0;
        out[(size_t)4 * N + (size_t)ray * 3 + 1] = k1;
        out[(size_t)4 * N + (size_t)ray * 3 + 2] = k2;
    }
}

extern "C" void kernel_launch(void* const* d_in, const int* in_sizes, int n_in,
                              void* d_out, int out_size, void* d_ws, size_t ws_size,
                              hipStream_t stream)
{
    const float* z    = (const float*)d_in[0];
    const float* sg   = (const float*)d_in[1];
    const float* rgb  = (const float*)d_in[2];
    const float* inst = (const float*)d_in[3];
    const float* bg   = (const float*)d_in[4];
    float* out = (float*)d_out;

    const int S = 128;
    int N = in_sizes[0] / S;                  // 65536
    int blocks = (N + 3) / 4;                 // 1 ray/wave, 4 waves/block
    render_kernel<<<blocks, 256, 0, stream>>>(z, sg, rgb, inst, bg, out, N);
}